// Round 3
// baseline (116.281 us; speedup 1.0000x reference)
//
#include <hip/hip_runtime.h>

#define NUM_CLASSES 100000
#define FEAT_DIM    256
#define BATCH       16384
#define ALPHA       0.5f
#define EPS_        1e-6f

typedef float f4 __attribute__((ext_vector_type(4)));
typedef f4 __attribute__((aligned(4))) f4_u;   // dest out+1 is only 4B-aligned

// --- ws layout (bytes) ---
#define OFF_COUNTS    0u                         // 100000 * 4 = 400000
#define OFF_SLOT      400000u                    // 100000 * 4
#define OFF_NSLOTS    800000u                    // 4
#define OFF_SUMS      802816u                    // 16384 * 256 * 4 = 16777216 (1KB aligned)
#define OFF_PART2     (802816u + 16777216u)      // 16384 * 4
#define OFF_PART      (OFF_PART2 + 65536u)       // 16384 * 4

// K1: histogram + compact slot assignment (exactly one owner per touched class)
__global__ void count_slot_kernel(const int* __restrict__ target,
                                  int* __restrict__ counts,
                                  int* __restrict__ slot_of,
                                  int* __restrict__ nslots) {
    int i = blockIdx.x * blockDim.x + threadIdx.x;
    if (i < BATCH) {
        int t = target[i];
        int old = atomicAdd(&counts[t], 1);
        if (old == 0) slot_of[t] = atomicAdd(nslots, 1);
    }
}

// K2: wave per sample. Scatter-add features into per-class sums; store ||f||^2.
__global__ void accum_kernel(const float* __restrict__ features,
                             const int*   __restrict__ target,
                             const int*   __restrict__ slot_of,
                             float*       __restrict__ sums,
                             float*       __restrict__ partials) {
    const int wave = threadIdx.x >> 6;
    const int lane = threadIdx.x & 63;
    const int i = blockIdx.x * 4 + wave;          // BATCH % 4 == 0
    const int slot = slot_of[target[i]];          // wave-uniform

    const f4 f = *(const f4*)(features + (size_t)i * FEAT_DIM + lane * 4);
    float* s = sums + (size_t)slot * FEAT_DIM + lane * 4;
    atomicAdd(&s[0], f.x);
    atomicAdd(&s[1], f.y);
    atomicAdd(&s[2], f.z);
    atomicAdd(&s[3], f.w);

    float sq = f.x*f.x + f.y*f.y + f.z*f.z + f.w*f.w;
    #pragma unroll
    for (int off = 32; off > 0; off >>= 1)
        sq += __shfl_down(sq, off, 64);
    if (lane == 0) partials[i] = sq;              // plain store — no hot atomic
}

// K3: wave per class row. new_c = c - alpha*(cnt*c - sum_f)/(cnt+eps); loss partial.
__global__ void rewrite_kernel(const float* __restrict__ centers,
                               const int*   __restrict__ counts,
                               const int*   __restrict__ slot_of,
                               const float* __restrict__ sums,
                               float*       __restrict__ out_centers,  // d_out + 1
                               float*       __restrict__ partials2) {
    const int wave = threadIdx.x >> 6;
    const int lane = threadIdx.x & 63;
    const int row = blockIdx.x * 4 + wave;        // NUM_CLASSES % 4 == 0
    if (row >= NUM_CLASSES) return;

    const f4 c = *(const f4*)(centers + (size_t)row * FEAT_DIM + lane * 4);
    const int cnt = counts[row];                  // wave-uniform
    f4_u* dst = (f4_u*)(out_centers + (size_t)row * FEAT_DIM + lane * 4);

    if (cnt == 0) {                               // untouched: pure copy (85% of rows)
        *dst = c;
        return;
    }
    const int slot = slot_of[row];
    const f4 sf = *(const f4*)(sums + (size_t)slot * FEAT_DIM + lane * 4);
    const float fc  = (float)cnt;
    const float inv = ALPHA / (fc + EPS_);
    f4 o;
    o.x = c.x - inv * (fc * c.x - sf.x);
    o.y = c.y - inv * (fc * c.y - sf.y);
    o.z = c.z - inv * (fc * c.z - sf.z);
    o.w = c.w - inv * (fc * c.w - sf.w);
    *dst = o;

    // loss partial for this class: cnt*||c||^2 - 2*c.sum_f  (wave-uniform branch)
    float red = fc * (c.x*c.x + c.y*c.y + c.z*c.z + c.w*c.w)
              - 2.0f * (c.x*sf.x + c.y*sf.y + c.z*sf.z + c.w*sf.w);
    #pragma unroll
    for (int off = 32; off > 0; off >>= 1)
        red += __shfl_down(red, off, 64);
    if (lane == 0) partials2[slot] = red;         // plain store
}

// K4: final reduce: loss = (sum ||f||^2 + sum class partials) / (B*D)
__global__ void reduce_loss(const float* __restrict__ partials,
                            const float* __restrict__ partials2,
                            float* __restrict__ out) {
    float s = 0.0f;
    for (int i = threadIdx.x; i < BATCH; i += 1024)
        s += partials[i] + partials2[i];          // untouched slots are 0
    #pragma unroll
    for (int off = 32; off > 0; off >>= 1)
        s += __shfl_down(s, off, 64);
    __shared__ float wsum[16];
    const int lane = threadIdx.x & 63;
    const int wid  = threadIdx.x >> 6;
    if (lane == 0) wsum[wid] = s;
    __syncthreads();
    if (threadIdx.x == 0) {
        float tot = 0.0f;
        #pragma unroll
        for (int k = 0; k < 16; ++k) tot += wsum[k];
        out[0] = tot * (1.0f / ((float)BATCH * (float)FEAT_DIM));
    }
}

extern "C" void kernel_launch(void* const* d_in, const int* in_sizes, int n_in,
                              void* d_out, int out_size, void* d_ws, size_t ws_size,
                              hipStream_t stream) {
    const float* centers  = (const float*)d_in[0];
    const float* features = (const float*)d_in[1];
    const int*   target   = (const int*)d_in[2];

    float* out         = (float*)d_out;
    float* out_centers = out + 1;

    char* ws = (char*)d_ws;
    int*   counts   = (int*)(ws + OFF_COUNTS);
    int*   slot_of  = (int*)(ws + OFF_SLOT);
    int*   nslots   = (int*)(ws + OFF_NSLOTS);
    float* sums     = (float*)(ws + OFF_SUMS);
    float* partials2= (float*)(ws + OFF_PART2);
    float* partials = (float*)(ws + OFF_PART);

    // zero counts+nslots (slot_of harmlessly included) and sums+partials2
    hipMemsetAsync(ws, 0, OFF_NSLOTS + 4, stream);
    hipMemsetAsync(ws + OFF_SUMS, 0, 16777216u + 65536u, stream);

    count_slot_kernel<<<(BATCH + 255) / 256, 256, 0, stream>>>(target, counts, slot_of, nslots);

    accum_kernel<<<BATCH / 4, 256, 0, stream>>>(features, target, slot_of, sums, partials);

    rewrite_kernel<<<NUM_CLASSES / 4, 256, 0, stream>>>(centers, counts, slot_of, sums,
                                                        out_centers, partials2);

    reduce_loss<<<1, 1024, 0, stream>>>(partials, partials2, out);
}